// Round 4
// baseline (381.492 us; speedup 1.0000x reference)
//
#include <hip/hip_runtime.h>
#include <hip/hip_bf16.h>

// Problem constants: B=16, T=1024, D=256
#define BB 16
#define TT 1024
#define DD 256
#define BM 64
#define BN 64
#define NGRP 64          // 16-row groups per batch (TT/16)
#define NKK 8            // K-chunks of 32 (DD/32)

typedef __attribute__((ext_vector_type(4))) float f32x4;
typedef __bf16 bf16x8 __attribute__((ext_vector_type(8)));
typedef unsigned short u16;
typedef u16 u16x8 __attribute__((ext_vector_type(8)));

// ws layout:
//   z_frag : offset 0,        16*64*8*64*8 u16 = 8388608 B
//   z2     : offset 8388608,  16*1024 f32 = 65536 B
//   accum  : offset 8454144,  32 f32 (num[16], den[16])
#define WS_Z2_OFF   8388608
#define WS_ACC_OFF  8454144

// One wave per row: z2[r] = sum(z[r,:]^2). Block 0 also zeroes the accums.
__global__ __launch_bounds__(256) void z2_kernel(
    const float* __restrict__ z, float* __restrict__ z2g,
    float* __restrict__ acc) {
    if (blockIdx.x == 0 && threadIdx.x < 2 * BB) acc[threadIdx.x] = 0.0f;
    const int lane = threadIdx.x & 63;
    const int wv   = threadIdx.x >> 6;
    const int row  = blockIdx.x * 4 + wv;          // flat b*T + t
    const f32x4 v = reinterpret_cast<const f32x4*>(z + (size_t)row * DD)[lane];
    float ss = v.x * v.x + v.y * v.y + v.z * v.z + v.w * v.w;
    #pragma unroll
    for (int off = 32; off; off >>= 1) ss += __shfl_xor(ss, off);
    if (lane == 0) z2g[row] = ss;
}

// One wave per (b, group, kk): emit the 16x32 bf16 fragment block in exact
// MFMA lane order. lane L holds z[b][g*16 + (L&15)][kk*32 + (L>>4)*8 + e].
__global__ __launch_bounds__(256) void frag_kernel(
    const float* __restrict__ z, u16* __restrict__ zf) {
    const int lane = threadIdx.x & 63;
    const int wv   = threadIdx.x >> 6;
    const int wid  = blockIdx.x * 4 + wv;          // 0 .. B*64*8-1
    const int b    = wid >> 9;
    const int rem  = wid & 511;
    const int g    = rem >> 3;
    const int kk   = rem & 7;
    const int lane15 = lane & 15;
    const int quad   = lane >> 4;

    const float* src = z + (((size_t)b * TT + g * 16 + lane15) * DD
                            + kk * 32 + quad * 8);
    const f32x4 v0 = reinterpret_cast<const f32x4*>(src)[0];
    const f32x4 v1 = reinterpret_cast<const f32x4*>(src)[1];
    float f[8] = {v0.x, v0.y, v0.z, v0.w, v1.x, v1.y, v1.z, v1.w};
    u16x8 pk;
    #pragma unroll
    for (int e = 0; e < 8; ++e) {
        __hip_bfloat16 h = __float2bfloat16(f[e]);
        pk[e] = *reinterpret_cast<const u16*>(&h);
    }
    reinterpret_cast<u16x8*>(zf)[(size_t)wid * 64 + lane] = pk;
}

// Main: 64x64 (t,s) tile per block, 4 waves each a 16x64 strip.
// Phase A: A-frag loads (L2). Phase B: k-loop B-frag loads + MFMA (L2).
// Phase C: all 16 gt float4 loads issued back-to-back into registers (HBM,
//          ~16 KB in flight per wave). Phase D: epilogue consumes them.
// No LDS staging, no barrier before the final 8-float reduction buffer.
__global__ __launch_bounds__(256, 4) void psl_main(
    const u16* __restrict__ zf, const float* __restrict__ z2g,
    const float* __restrict__ gt, float* __restrict__ accum) {
    __shared__ float rbuf[8];

    const int tid  = threadIdx.x;
    const int lane = tid & 63;
    const int wv   = tid >> 6;
    const int b    = blockIdx.z;
    const int t0   = blockIdx.y * BM;
    const int s0   = blockIdx.x * BN;
    const int lane15 = lane & 15;
    const int quad   = lane >> 4;

    const bf16x8* fragp = reinterpret_cast<const bf16x8*>(zf);
    const int gA  = blockIdx.y * 4 + wv;           // this wave's t-group
    const int gB0 = blockIdx.x * 4;                // s-groups j=0..3

    // ---- Phase A: A-fragments (8 coalesced 16B/lane loads, L2-hot) ----
    bf16x8 af[NKK];
    #pragma unroll
    for (int kk = 0; kk < NKK; ++kk)
        af[kk] = fragp[(((size_t)b * NGRP + gA) * NKK + kk) * 64 + lane];

    // ---- Phase B: MFMA Gram ----
    f32x4 acc[4];
    #pragma unroll
    for (int j = 0; j < 4; ++j) acc[j] = (f32x4){0.f, 0.f, 0.f, 0.f};

    #pragma unroll
    for (int j = 0; j < 4; ++j) {
        const size_t bbase = ((size_t)b * NGRP + gB0 + j) * NKK;
        #pragma unroll
        for (int kk = 0; kk < NKK; ++kk) {
            bf16x8 bfj = fragp[(bbase + kk) * 64 + lane];
            acc[j] = __builtin_amdgcn_mfma_f32_16x16x32_bf16(af[kk], bfj, acc[j], 0, 0, 0);
        }
    }

    // ---- Phase C: issue all 16 gt loads back-to-back ----
    const int trow0 = wv * 16 + quad * 4;          // C layout: row = quad*4 + reg
    f32x4 g[4][4];                                 // [i=row][j=col-block]
    {
        const f32x4* base = reinterpret_cast<const f32x4*>(gt)
                          + (((size_t)b * TT + t0 + trow0) * TT + s0 + lane15);
        #pragma unroll
        for (int i = 0; i < 4; ++i) {
            const f32x4* rowp = base + (size_t)i * TT;
            #pragma unroll
            for (int j = 0; j < 4; ++j)
                g[i][j] = rowp[j * 16];
        }
    }

    // ---- Phase D: epilogue ----
    const float c_yx = 1.0f / (2.0f * 0.09f * 0.09f);
    const float c_hw = 1.0f / (2.0f * 0.3f * 0.3f);
    float z2t_r[4];
    #pragma unroll
    for (int i = 0; i < 4; ++i) z2t_r[i] = z2g[b * TT + t0 + trow0 + i];

    float nsum = 0.0f, dsum = 0.0f;
    #pragma unroll
    for (int j = 0; j < 4; ++j) {
        const float z2s_r = z2g[b * TT + s0 + j * 16 + lane15];
        #pragma unroll
        for (int i = 0; i < 4; ++i) {
            const f32x4 dv = g[i][j];
            const float e = (dv.x * dv.x + dv.y * dv.y) * c_yx
                          + (dv.z * dv.z + dv.w * dv.w) * c_hw;
            const float wgt = __expf(-e);
            nsum += wgt * (z2t_r[i] + z2s_r - 2.0f * acc[j][i]);
            dsum += wgt;
        }
    }

    #pragma unroll
    for (int off = 32; off; off >>= 1) {
        nsum += __shfl_xor(nsum, off);
        dsum += __shfl_xor(dsum, off);
    }
    if (lane == 0) { rbuf[wv] = nsum; rbuf[4 + wv] = dsum; }
    __syncthreads();
    if (tid == 0) {
        const float n = rbuf[0] + rbuf[1] + rbuf[2] + rbuf[3];
        const float d = rbuf[4] + rbuf[5] + rbuf[6] + rbuf[7];
        atomicAdd(&accum[b], n);
        atomicAdd(&accum[BB + b], d);
    }
}

__global__ void finalize_kernel(const float* __restrict__ accum,
                                float* __restrict__ out) {
    if (threadIdx.x == 0 && blockIdx.x == 0) {
        float s = 0.0f;
        for (int b = 0; b < BB; ++b)
            s += accum[b] / fmaxf(accum[BB + b], 1e-6f);
        out[0] = s / (float)BB;
    }
}

extern "C" void kernel_launch(void* const* d_in, const int* in_sizes, int n_in,
                              void* d_out, int out_size, void* d_ws, size_t ws_size,
                              hipStream_t stream) {
    const float* z  = (const float*)d_in[0];   // (B,T,D) fp32
    const float* gt = (const float*)d_in[1];   // (B,T,T,4) fp32
    float* out = (float*)d_out;

    char* ws = (char*)d_ws;
    u16*   zf    = (u16*)ws;
    float* z2g   = (float*)(ws + WS_Z2_OFF);
    float* accum = (float*)(ws + WS_ACC_OFF);

    z2_kernel<<<BB * TT / 4, 256, 0, stream>>>(z, z2g, accum);
    frag_kernel<<<BB * NGRP * NKK / 4, 256, 0, stream>>>(z, zf);
    dim3 grid(TT / BN, TT / BM, BB);
    psl_main<<<grid, 256, 0, stream>>>(zf, z2g, gt, accum);
    finalize_kernel<<<1, 64, 0, stream>>>(accum, out);
}